// Round 14
// baseline (247.231 us; speedup 1.0000x reference)
//
#include <hip/hip_runtime.h>
#include <hip/hip_bf16.h>
#include <math.h>

typedef __hip_bfloat16 bf16;
typedef __attribute__((ext_vector_type(8))) short short8;
typedef __attribute__((ext_vector_type(4))) float floatx4;
typedef __attribute__((ext_vector_type(4))) unsigned uintx4;

#define GLDS16(g, l) __builtin_amdgcn_global_load_lds( \
    (const __attribute__((address_space(1))) void*)(g), \
    (__attribute__((address_space(3))) void*)(l), 16, 0, 0)

__device__ __forceinline__ bf16 f2bf(float v) { return __float2bfloat16(v); }

__device__ __forceinline__ unsigned cvtpk(float a, float b) {
  unsigned r;
  asm volatile("v_cvt_pk_bf16_f32 %0, %1, %2" : "=v"(r) : "v"(a), "v"(b));
  return r;
}

// ---------------- weight convert + transpose: w[K][N] f32 -> wT[N][K] bf16
__global__ __launch_bounds__(256) void kconvT(const float* __restrict__ w,
                                              bf16* __restrict__ wT,
                                              int K, int N) {
  __shared__ float tile[32][33];
  const int n0 = blockIdx.x * 32, k0 = blockIdx.y * 32;
  const int tc = threadIdx.x & 31, tr = threadIdx.x >> 5;
#pragma unroll
  for (int p = 0; p < 4; p++)
    tile[tr + p * 8][tc] = w[(size_t)(k0 + tr + p * 8) * N + n0 + tc];
  __syncthreads();
#pragma unroll
  for (int p = 0; p < 4; p++)
    wT[(size_t)(n0 + tr + p * 8) * K + k0 + tc] = f2bf(tile[tc][tr + p * 8]);
}

// ---------------- LayerNorm: f32 [rows][768] -> bf16
__global__ __launch_bounds__(256) void kln(const float* __restrict__ x,
                                           const float* __restrict__ gw,
                                           const float* __restrict__ bw,
                                           bf16* __restrict__ out) {
  const int row = blockIdx.x, tid = threadIdx.x;
  const float* xr = x + (size_t)row * 768;
  float v0 = xr[tid], v1 = xr[tid + 256], v2 = xr[tid + 512];
  float s = v0 + v1 + v2;
  float s2 = v0 * v0 + v1 * v1 + v2 * v2;
#pragma unroll
  for (int off = 1; off < 64; off <<= 1) {
    s += __shfl_xor(s, off);
    s2 += __shfl_xor(s2, off);
  }
  __shared__ float red[8];
  const int wid = tid >> 6, lane = tid & 63;
  if (lane == 0) { red[wid] = s; red[4 + wid] = s2; }
  __syncthreads();
  s = red[0] + red[1] + red[2] + red[3];
  s2 = red[4] + red[5] + red[6] + red[7];
  const float mu = s * (1.f / 768.f);
  const float rst = rsqrtf(fmaxf(s2 * (1.f / 768.f) - mu * mu, 0.f) + 1e-5f);
  bf16* orow = out + (size_t)row * 768;
  orow[tid] = f2bf((v0 - mu) * rst * gw[tid] + bw[tid]);
  orow[tid + 256] = f2bf((v1 - mu) * rst * gw[tid + 256] + bw[tid + 256]);
  orow[tid + 512] = f2bf((v2 - mu) * rst * gw[tid + 512] + bw[tid + 512]);
}

// ---------------- V transpose: qkv[b*T+t][1536 + h*64 + d] -> VT[b][h][d][t]
__global__ __launch_bounds__(256) void kxpose(const bf16* __restrict__ qkv,
                                              bf16* __restrict__ VT) {
  const int T = 2048, C3 = 2304;
  const int t0 = blockIdx.x * 64, h = blockIdx.y, b = blockIdx.z;
  const int tid = threadIdx.x;
  __shared__ short tile[64][66];
  const bf16* src = qkv + (size_t)b * T * C3 + 1536 + h * 64;
  const int tr = tid >> 3, c = tid & 7;
#pragma unroll
  for (int p = 0; p < 2; p++) {
    short8 v = *(const short8*)(src + (size_t)(t0 + tr + p * 32) * C3 + c * 8);
    *(short8*)&tile[tr + p * 32][c * 8] = v;
  }
  __syncthreads();
  bf16* dst = VT + ((size_t)(b * 12 + h) * 64) * T + t0;
#pragma unroll
  for (int p = 0; p < 2; p++) {
    const int d = (tid >> 3) + p * 32, tc = tid & 7;
    short8 v;
#pragma unroll
    for (int j = 0; j < 8; j++) v[j] = tile[tc * 8 + j][d];
    *(short8*)(dst + (size_t)d * T + tc * 8) = v;
  }
}

// ---------------- split-K init: out[r][c] = resid[r][c] + bias[c]  (f32x4)
__global__ __launch_bounds__(256) void kinit(const float* __restrict__ resid,
                                             const float* __restrict__ bias,
                                             float* __restrict__ out, int N) {
  const size_t i4 = ((size_t)blockIdx.x * 256 + threadIdx.x) * 4;
  const floatx4 r = *(const floatx4*)(resid + i4);
  const floatx4 bv = *(const floatx4*)(bias + (i4 % N));
  *(floatx4*)(out + i4) = r + bv;
}

// ---------------- GEMM v3 (non-split): depth-3 pipeline, counted vmcnt,
// XCD-chunked swizzle, XOR bank swizzle. EPI 0: +bias->bf16  EPI 2: GELU->bf16
template <int BN, int EPI>
__global__ __launch_bounds__(256, 2) void kgemm(
    const bf16* __restrict__ A, const bf16* __restrict__ BT,
    const float* __restrict__ bias, const float* __restrict__ resid,
    bf16* __restrict__ outb, float* __restrict__ outf, int M, int N, int K,
    int NXB) {
  __shared__ bf16 As[3][128 * 32];
  __shared__ bf16 Bs[3][BN * 32];
  const int tid = threadIdx.x;
  const int wid = tid >> 6, lane = tid & 63, g = lane >> 4, q = lane & 15;
  constexpr int FM = (BN == 128) ? 4 : 2;
  constexpr int FN = 4;
  constexpr int WM = (BN == 128) ? 64 : 32;
  const int wr = (BN == 128) ? (wid >> 1) : wid;
  const int wc = (BN == 128) ? (wid & 1) : 0;

  const int bid = blockIdx.x;
  const int lb = (bid & 7) * ((int)gridDim.x >> 3) + (bid >> 3);
  const int row0 = (lb / NXB) * 128, col0 = (lb % NXB) * BN;

  floatx4 acc[FM][FN] = {};
  const int r0 = tid >> 2;
  const int c0 = (((tid & 3) ^ ((r0 >> 1) & 3))) * 8;
  const int lsl = (g ^ ((q >> 1) & 3)) * 16;
  const bf16* Ab = A + (size_t)row0 * K;
  const bf16* Bb = BT + (size_t)col0 * K;

  auto STAGE = [&](int kk, int buf) {
    GLDS16(Ab + (size_t)r0 * K + kk + c0, (char*)&As[buf][0] + wid * 1024);
    GLDS16(Ab + (size_t)(r0 + 64) * K + kk + c0,
           (char*)&As[buf][0] + 4096 + wid * 1024);
    GLDS16(Bb + (size_t)r0 * K + kk + c0, (char*)&Bs[buf][0] + wid * 1024);
    if constexpr (BN == 128)
      GLDS16(Bb + (size_t)(r0 + 64) * K + kk + c0,
             (char*)&Bs[buf][0] + 4096 + wid * 1024);
  };

  const int nk = K >> 5;
  STAGE(0, 0);
  STAGE(32, 1);

  for (int kt = 0; kt < nk; kt++) {
    if (kt + 2 < nk) {
      STAGE((kt + 2) << 5, (kt + 2) % 3);
      if constexpr (BN == 128) asm volatile("s_waitcnt vmcnt(8)");
      else asm volatile("s_waitcnt vmcnt(6)");
    } else if (kt + 1 < nk) {
      if constexpr (BN == 128) asm volatile("s_waitcnt vmcnt(4)");
      else asm volatile("s_waitcnt vmcnt(3)");
    } else {
      asm volatile("s_waitcnt vmcnt(0)");
    }
    __syncthreads();

    const char* Ac = (const char*)&As[kt % 3][0];
    const char* Bc = (const char*)&Bs[kt % 3][0];
    short8 af[FM], bfr[FN];
#pragma unroll
    for (int m = 0; m < FM; m++)
      af[m] = *(const short8*)(Ac + (wr * WM + m * 16 + q) * 64 + lsl);
#pragma unroll
    for (int n = 0; n < FN; n++)
      bfr[n] = *(const short8*)(Bc + (wc * 64 + n * 16 + q) * 64 + lsl);
#pragma unroll
    for (int m = 0; m < FM; m++)
#pragma unroll
      for (int n = 0; n < FN; n++)
        acc[m][n] =
            __builtin_amdgcn_mfma_f32_16x16x32_bf16(af[m], bfr[n], acc[m][n], 0, 0, 0);
    __syncthreads();
  }

#pragma unroll
  for (int n = 0; n < FN; n++) {
    const int col = col0 + wc * 64 + n * 16 + q;
    const float bv = bias[col];
#pragma unroll
    for (int m = 0; m < FM; m++) {
      const int rowb = row0 + wr * WM + m * 16 + g * 4;
#pragma unroll
      for (int r = 0; r < 4; r++) {
        const size_t idx = (size_t)(rowb + r) * N + col;
        const float v = acc[m][n][r] + bv;
        if (EPI == 0) {
          outb[idx] = f2bf(v);
        } else {
          const float t = tanhf(0.7978845608028654f * (v + 0.044715f * v * v * v));
          outb[idx] = f2bf(0.5f * v * (1.0f + t));
        }
      }
    }
  }
}

// ---------------- split-K GEMM: thin-N shapes (N=768 -> 384 tiles = 1.5
// blocks/CU, grid-limited at 14% occupancy, R13). KS splits of K raise the
// grid to 3-6 blocks/CU; partials accumulate into a kinit-prepared f32
// output via HW f32 atomics. Same depth-3 pipeline + swizzles as kgemm.
template <int BN>
__global__ __launch_bounds__(256, 2) void kgemmsk(
    const bf16* __restrict__ A, const bf16* __restrict__ BT,
    float* __restrict__ outf, int M, int N, int K, int NXB, int TILES,
    int KSL) {
  __shared__ bf16 As[3][128 * 32];
  __shared__ bf16 Bs[3][BN * 32];
  const int tid = threadIdx.x;
  const int wid = tid >> 6, lane = tid & 63, g = lane >> 4, q = lane & 15;
  constexpr int FM = 2;
  constexpr int FN = 4;
  constexpr int WM = 32;
  const int wr = wid, wc = 0;

  const int bid = blockIdx.x;
  const int lb = (bid & 7) * ((int)gridDim.x >> 3) + (bid >> 3);
  const int ks = lb / TILES, t = lb % TILES;
  const int row0 = (t / NXB) * 128, col0 = (t % NXB) * BN;

  floatx4 acc[FM][FN] = {};
  const int r0 = tid >> 2;
  const int c0 = (((tid & 3) ^ ((r0 >> 1) & 3))) * 8;
  const int lsl = (g ^ ((q >> 1) & 3)) * 16;
  const bf16* Ab = A + (size_t)row0 * K + ks * KSL;
  const bf16* Bb = BT + (size_t)col0 * K + ks * KSL;

  auto STAGE = [&](int kk, int buf) {
    GLDS16(Ab + (size_t)r0 * K + kk + c0, (char*)&As[buf][0] + wid * 1024);
    GLDS16(Ab + (size_t)(r0 + 64) * K + kk + c0,
           (char*)&As[buf][0] + 4096 + wid * 1024);
    GLDS16(Bb + (size_t)r0 * K + kk + c0, (char*)&Bs[buf][0] + wid * 1024);
  };

  const int nk = KSL >> 5;
  STAGE(0, 0);
  STAGE(32, 1);

  for (int kt = 0; kt < nk; kt++) {
    if (kt + 2 < nk) {
      STAGE((kt + 2) << 5, (kt + 2) % 3);
      asm volatile("s_waitcnt vmcnt(6)");
    } else if (kt + 1 < nk) {
      asm volatile("s_waitcnt vmcnt(3)");
    } else {
      asm volatile("s_waitcnt vmcnt(0)");
    }
    __syncthreads();

    const char* Ac = (const char*)&As[kt % 3][0];
    const char* Bc = (const char*)&Bs[kt % 3][0];
    short8 af[FM], bfr[FN];
#pragma unroll
    for (int m = 0; m < FM; m++)
      af[m] = *(const short8*)(Ac + (wr * WM + m * 16 + q) * 64 + lsl);
#pragma unroll
    for (int n = 0; n < FN; n++)
      bfr[n] = *(const short8*)(Bc + (wc * 64 + n * 16 + q) * 64 + lsl);
#pragma unroll
    for (int m = 0; m < FM; m++)
#pragma unroll
      for (int n = 0; n < FN; n++)
        acc[m][n] =
            __builtin_amdgcn_mfma_f32_16x16x32_bf16(af[m], bfr[n], acc[m][n], 0, 0, 0);
    __syncthreads();
  }

#pragma unroll
  for (int n = 0; n < FN; n++) {
    const int col = col0 + wc * 64 + n * 16 + q;
#pragma unroll
    for (int m = 0; m < FM; m++) {
      const int rowb = row0 + wr * WM + m * 16 + g * 4;
#pragma unroll
      for (int r = 0; r < 4; r++) {
        const size_t idx = (size_t)(rowb + r) * N + col;
        unsafeAtomicAdd(&outf[idx], acc[m][n][r]);
      }
    }
  }
}

// ---------------- causal flash attention v9 (unchanged — verified)
__global__ __launch_bounds__(256, 2) void kattn(const bf16* __restrict__ qkv,
                                                const bf16* __restrict__ VT,
                                                bf16* __restrict__ y) {
  const int T = 2048, C3 = 2304;
  const int tid = threadIdx.x;
  const int w = tid >> 6, lane = tid & 63;
  const int g = lane >> 4, qi = lane & 15;

  const int bid = blockIdx.x;
  const int lb = (bid & 7) * 96 + (bid >> 3);
  const int qblk = 31 - (lb & 31);
  const int h = (lb >> 5) % 12, b = (lb >> 5) / 12;
  const int q0w = qblk * 64 + w * 16;
  const int qrow = q0w + qi;

  const bf16* Qb = qkv + (size_t)b * T * C3 + h * 64;
  const char* Ksrc = (const char*)(Qb + 768);
  const char* Vsrc = (const char*)(VT + (size_t)(b * 12 + h) * 64 * T);

  __shared__ __align__(16) char smem[32768];

  const int nt = qblk + 1;

  short8 qf[2];
#pragma unroll
  for (int s = 0; s < 2; s++)
    qf[s] = *(const short8*)(Qb + (size_t)qrow * C3 + s * 32 + g * 8);

  const int kvb = (qi >> 2) * 8 + (qi & 3);
  const unsigned swz = (unsigned)(((lane & 7) ^ (lane >> 3)) << 4);
  const int srow = lane >> 3;

  float m_run = -1e30f, l_run = 0.f;
  floatx4 o[4] = {};

#define STAGE(t)                                                                   \
  {                                                                                \
    char* base_ = smem + ((t) & 1) * 16384;                                        \
    const int kv0_ = (t) * 64;                                                     \
    _Pragma("unroll")                                                              \
    for (int j = 0; j < 2; j++) {                                                  \
      const int c_ = w * 2 + j;                                                    \
      GLDS16(Ksrc + (size_t)(kv0_ + c_ * 8 + srow) * 4608 + swz, base_ + c_ * 1024); \
      GLDS16(Vsrc + (size_t)(c_ * 8 + srow) * 4096 + kv0_ * 2 + swz,               \
             base_ + 8192 + c_ * 1024);                                            \
    }                                                                              \
  }

  STAGE(0);
  asm volatile("s_waitcnt vmcnt(0)");
  __syncthreads();

  for (int t = 0; t < nt; t++) {
    if (t + 1 < nt) STAGE(t + 1);
    const char* Kl = smem + (t & 1) * 16384;
    const char* Vl = Kl + 8192;
    const int kv0 = t * 64;

    short8 kf[8];
#pragma unroll
    for (int c = 0; c < 4; c++) {
      const int R = kvb + (c & 1) * 4 + (c >> 1) * 32;
#pragma unroll
      for (int s = 0; s < 2; s++)
        kf[c * 2 + s] =
            *(const short8*)(Kl + R * 128 + (((s * 4 + g) ^ (R & 7)) << 4));
    }
    short8 vfr[8];
#pragma unroll
    for (int ks = 0; ks < 2; ks++)
#pragma unroll
      for (int n = 0; n < 4; n++) {
        const int R2 = n * 16 + qi;
        vfr[ks * 4 + n] =
            *(const short8*)(Vl + R2 * 128 + (((ks * 4 + g) ^ (R2 & 7)) << 4));
      }

    floatx4 sacc[4] = {};
#pragma unroll
    for (int c = 0; c < 4; c++)
#pragma unroll
      for (int s = 0; s < 2; s++)
        sacc[c] =
            __builtin_amdgcn_mfma_f32_16x16x32_bf16(kf[c * 2 + s], qf[s], sacc[c], 0, 0, 0);

    if (kv0 + 63 > q0w) {
#pragma unroll
      for (int c = 0; c < 4; c++)
#pragma unroll
        for (int r = 0; r < 4; r++) {
          const int kv = kv0 + g * 8 + (c & 1) * 4 + r + (c >> 1) * 32;
          if (kv > qrow) sacc[c][r] = -1e30f;
        }
    }
    float mx = sacc[0][0];
#pragma unroll
    for (int c = 0; c < 4; c++)
#pragma unroll
      for (int r = 0; r < 4; r++) mx = fmaxf(mx, sacc[c][r]);
    mx = fmaxf(mx, __shfl_xor(mx, 16));
    mx = fmaxf(mx, __shfl_xor(mx, 32));
    mx *= 0.125f;
    const float mn = fmaxf(m_run, mx);
    const float al = __expf(m_run - mn);
    float ps = 0.f;
    unsigned pk[8];
#pragma unroll
    for (int c = 0; c < 4; c++) {
      float p0 = __expf(fmaf(sacc[c][0], 0.125f, -mn));
      float p1 = __expf(fmaf(sacc[c][1], 0.125f, -mn));
      float p2 = __expf(fmaf(sacc[c][2], 0.125f, -mn));
      float p3 = __expf(fmaf(sacc[c][3], 0.125f, -mn));
      ps += (p0 + p1) + (p2 + p3);
      pk[c * 2] = cvtpk(p0, p1);
      pk[c * 2 + 1] = cvtpk(p2, p3);
    }
    ps += __shfl_xor(ps, 16);
    ps += __shfl_xor(ps, 32);
    l_run = l_run * al + ps;
    m_run = mn;
#pragma unroll
    for (int n = 0; n < 4; n++) o[n] *= al;

#pragma unroll
    for (int ks = 0; ks < 2; ks++) {
      uintx4 pu;
      pu.x = pk[ks * 4 + 0];
      pu.y = pk[ks * 4 + 1];
      pu.z = pk[ks * 4 + 2];
      pu.w = pk[ks * 4 + 3];
      const short8 pf = __builtin_bit_cast(short8, pu);
#pragma unroll
      for (int n = 0; n < 4; n++)
        o[n] = __builtin_amdgcn_mfma_f32_16x16x32_bf16(vfr[ks * 4 + n], pf, o[n], 0, 0, 0);
    }

    asm volatile("s_waitcnt vmcnt(0)");
    __syncthreads();
  }
#undef STAGE

  const float inv = 1.0f / l_run;
  bf16* yr = y + (size_t)(b * T + qrow) * 768 + h * 64;
#pragma unroll
  for (int n = 0; n < 4; n++) {
    uint2 pr;
    pr.x = cvtpk(o[n][0] * inv, o[n][1] * inv);
    pr.y = cvtpk(o[n][2] * inv, o[n][3] * inv);
    *(uint2*)(yr + n * 16 + g * 4) = pr;
  }
}

// ---------------- host side
extern "C" void kernel_launch(void* const* d_in, const int* in_sizes, int n_in,
                              void* d_out, int out_size, void* d_ws, size_t ws_size,
                              hipStream_t stream) {
  const float* x      = (const float*)d_in[0];
  const float* ln1_g  = (const float*)d_in[1];
  const float* ln1_b  = (const float*)d_in[2];
  const float* w_attn = (const float*)d_in[3];
  const float* b_attn = (const float*)d_in[4];
  const float* w_proj = (const float*)d_in[5];
  const float* b_proj = (const float*)d_in[6];
  const float* ln2_g  = (const float*)d_in[7];
  const float* ln2_b  = (const float*)d_in[8];
  const float* w_fc   = (const float*)d_in[9];
  const float* b_fc   = (const float*)d_in[10];
  const float* w_fc2  = (const float*)d_in[11];
  const float* b_fc2  = (const float*)d_in[12];
  float* out = (float*)d_out;

  const int M = 4096;  // B*T
  char* p = (char*)d_ws;
  bf16* wT_attn = (bf16*)p; p += (size_t)2304 * 768 * 2;
  bf16* wT_proj = (bf16*)p; p += (size_t)768 * 768 * 2;
  bf16* wT_fc   = (bf16*)p; p += (size_t)3072 * 768 * 2;
  bf16* wT_fc2  = (bf16*)p; p += (size_t)768 * 3072 * 2;
  bf16* h       = (bf16*)p; p += (size_t)M * 768 * 2;
  bf16* qkv     = (bf16*)p;
  bf16* yb      = (bf16*)(p + (size_t)M * 2304 * 2);
  bf16* act     = qkv;      p += (size_t)M * 2304 * 2 + (size_t)M * 768 * 2;
  float* x1     = (float*)p;
  bf16* VT      = (bf16*)p;  // aliases x1: VT dead before x1 is written

  // weights -> bf16 transposed
  kconvT<<<dim3(2304 / 32, 768 / 32), 256, 0, stream>>>(w_attn, wT_attn, 768, 2304);
  kconvT<<<dim3(768 / 32, 768 / 32), 256, 0, stream>>>(w_proj, wT_proj, 768, 768);
  kconvT<<<dim3(3072 / 32, 768 / 32), 256, 0, stream>>>(w_fc, wT_fc, 768, 3072);
  kconvT<<<dim3(768 / 32, 3072 / 32), 256, 0, stream>>>(w_fc2, wT_fc2, 3072, 768);

  // attention branch
  kln<<<M, 256, 0, stream>>>(x, ln1_g, ln1_b, h);
  kgemm<128, 0><<<dim3(18 * 32), 256, 0, stream>>>(
      h, wT_attn, b_attn, nullptr, qkv, nullptr, M, 2304, 768, 18);
  kxpose<<<dim3(32, 12, 2), 256, 0, stream>>>(qkv, VT);
  kattn<<<dim3(768), 256, 0, stream>>>(qkv, VT, yb);
  // proj (split-K=2): x1 = x + b_proj, then atomic partials
  kinit<<<dim3(M * 768 / 1024), 256, 0, stream>>>(x, b_proj, x1, 768);
  kgemmsk<64><<<dim3(768), 256, 0, stream>>>(
      yb, wT_proj, x1, M, 768, 768, 12, 384, 384);

  // MLP branch
  kln<<<M, 256, 0, stream>>>(x1, ln2_g, ln2_b, h);
  kgemm<128, 2><<<dim3(24 * 32), 256, 0, stream>>>(
      h, wT_fc, b_fc, nullptr, act, nullptr, M, 3072, 768, 24);
  // fc2 (split-K=4): out = x1 + b_fc2, then atomic partials
  kinit<<<dim3(M * 768 / 1024), 256, 0, stream>>>(x1, b_fc2, out, 768);
  kgemmsk<64><<<dim3(1536), 256, 0, stream>>>(
      act, wT_fc2, out, M, 768, 3072, 12, 384, 768);
}

// Round 15
// 209.039 us; speedup vs baseline: 1.1827x; 1.1827x over previous
//
#include <hip/hip_runtime.h>
#include <hip/hip_bf16.h>
#include <math.h>

typedef __hip_bfloat16 bf16;
typedef __attribute__((ext_vector_type(8))) short short8;
typedef __attribute__((ext_vector_type(4))) float floatx4;
typedef __attribute__((ext_vector_type(4))) unsigned uintx4;

#define GLDS16(g, l) __builtin_amdgcn_global_load_lds( \
    (const __attribute__((address_space(1))) void*)(g), \
    (__attribute__((address_space(3))) void*)(l), 16, 0, 0)

__device__ __forceinline__ bf16 f2bf(float v) { return __float2bfloat16(v); }

__device__ __forceinline__ unsigned cvtpk(float a, float b) {
  unsigned r;
  asm volatile("v_cvt_pk_bf16_f32 %0, %1, %2" : "=v"(r) : "v"(a), "v"(b));
  return r;
}

// ---------------- weight convert + transpose: w[K][N] f32 -> wT[N][K] bf16
__global__ __launch_bounds__(256) void kconvT(const float* __restrict__ w,
                                              bf16* __restrict__ wT,
                                              int K, int N) {
  __shared__ float tile[32][33];
  const int n0 = blockIdx.x * 32, k0 = blockIdx.y * 32;
  const int tc = threadIdx.x & 31, tr = threadIdx.x >> 5;
#pragma unroll
  for (int p = 0; p < 4; p++)
    tile[tr + p * 8][tc] = w[(size_t)(k0 + tr + p * 8) * N + n0 + tc];
  __syncthreads();
#pragma unroll
  for (int p = 0; p < 4; p++)
    wT[(size_t)(n0 + tr + p * 8) * K + k0 + tc] = f2bf(tile[tc][tr + p * 8]);
}

// ---------------- LayerNorm: f32 [rows][768] -> bf16
__global__ __launch_bounds__(256) void kln(const float* __restrict__ x,
                                           const float* __restrict__ gw,
                                           const float* __restrict__ bw,
                                           bf16* __restrict__ out) {
  const int row = blockIdx.x, tid = threadIdx.x;
  const float* xr = x + (size_t)row * 768;
  float v0 = xr[tid], v1 = xr[tid + 256], v2 = xr[tid + 512];
  float s = v0 + v1 + v2;
  float s2 = v0 * v0 + v1 * v1 + v2 * v2;
#pragma unroll
  for (int off = 1; off < 64; off <<= 1) {
    s += __shfl_xor(s, off);
    s2 += __shfl_xor(s2, off);
  }
  __shared__ float red[8];
  const int wid = tid >> 6, lane = tid & 63;
  if (lane == 0) { red[wid] = s; red[4 + wid] = s2; }
  __syncthreads();
  s = red[0] + red[1] + red[2] + red[3];
  s2 = red[4] + red[5] + red[6] + red[7];
  const float mu = s * (1.f / 768.f);
  const float rst = rsqrtf(fmaxf(s2 * (1.f / 768.f) - mu * mu, 0.f) + 1e-5f);
  bf16* orow = out + (size_t)row * 768;
  orow[tid] = f2bf((v0 - mu) * rst * gw[tid] + bw[tid]);
  orow[tid + 256] = f2bf((v1 - mu) * rst * gw[tid + 256] + bw[tid + 256]);
  orow[tid + 512] = f2bf((v2 - mu) * rst * gw[tid + 512] + bw[tid + 512]);
}

// ---------------- V transpose: qkv[b*T+t][1536 + h*64 + d] -> VT[b][h][d][t]
__global__ __launch_bounds__(256) void kxpose(const bf16* __restrict__ qkv,
                                              bf16* __restrict__ VT) {
  const int T = 2048, C3 = 2304;
  const int t0 = blockIdx.x * 64, h = blockIdx.y, b = blockIdx.z;
  const int tid = threadIdx.x;
  __shared__ short tile[64][66];
  const bf16* src = qkv + (size_t)b * T * C3 + 1536 + h * 64;
  const int tr = tid >> 3, c = tid & 7;
#pragma unroll
  for (int p = 0; p < 2; p++) {
    short8 v = *(const short8*)(src + (size_t)(t0 + tr + p * 32) * C3 + c * 8);
    *(short8*)&tile[tr + p * 32][c * 8] = v;
  }
  __syncthreads();
  bf16* dst = VT + ((size_t)(b * 12 + h) * 64) * T + t0;
#pragma unroll
  for (int p = 0; p < 2; p++) {
    const int d = (tid >> 3) + p * 32, tc = tid & 7;
    short8 v;
#pragma unroll
    for (int j = 0; j < 8; j++) v[j] = tile[tc * 8 + j][d];
    *(short8*)(dst + (size_t)d * T + tc * 8) = v;
  }
}

// ---------------- GEMM v3 (BM=128): depth-3 pipeline, counted vmcnt,
// XCD-chunked swizzle, XOR bank swizzle. EPI 0: +bias->bf16  EPI 2: GELU->bf16
template <int BN, int EPI>
__global__ __launch_bounds__(256, 2) void kgemm(
    const bf16* __restrict__ A, const bf16* __restrict__ BT,
    const float* __restrict__ bias, const float* __restrict__ resid,
    bf16* __restrict__ outb, float* __restrict__ outf, int M, int N, int K,
    int NXB) {
  __shared__ bf16 As[3][128 * 32];
  __shared__ bf16 Bs[3][BN * 32];
  const int tid = threadIdx.x;
  const int wid = tid >> 6, lane = tid & 63, g = lane >> 4, q = lane & 15;
  constexpr int FM = (BN == 128) ? 4 : 2;
  constexpr int FN = 4;
  constexpr int WM = (BN == 128) ? 64 : 32;
  const int wr = (BN == 128) ? (wid >> 1) : wid;
  const int wc = (BN == 128) ? (wid & 1) : 0;

  const int bid = blockIdx.x;
  const int lb = (bid & 7) * ((int)gridDim.x >> 3) + (bid >> 3);
  const int row0 = (lb / NXB) * 128, col0 = (lb % NXB) * BN;

  floatx4 acc[FM][FN] = {};
  const int r0 = tid >> 2;
  const int c0 = (((tid & 3) ^ ((r0 >> 1) & 3))) * 8;
  const int lsl = (g ^ ((q >> 1) & 3)) * 16;
  const bf16* Ab = A + (size_t)row0 * K;
  const bf16* Bb = BT + (size_t)col0 * K;

  auto STAGE = [&](int kk, int buf) {
    GLDS16(Ab + (size_t)r0 * K + kk + c0, (char*)&As[buf][0] + wid * 1024);
    GLDS16(Ab + (size_t)(r0 + 64) * K + kk + c0,
           (char*)&As[buf][0] + 4096 + wid * 1024);
    GLDS16(Bb + (size_t)r0 * K + kk + c0, (char*)&Bs[buf][0] + wid * 1024);
    if constexpr (BN == 128)
      GLDS16(Bb + (size_t)(r0 + 64) * K + kk + c0,
             (char*)&Bs[buf][0] + 4096 + wid * 1024);
  };

  const int nk = K >> 5;
  STAGE(0, 0);
  STAGE(32, 1);

  for (int kt = 0; kt < nk; kt++) {
    if (kt + 2 < nk) {
      STAGE((kt + 2) << 5, (kt + 2) % 3);
      if constexpr (BN == 128) asm volatile("s_waitcnt vmcnt(8)");
      else asm volatile("s_waitcnt vmcnt(6)");
    } else if (kt + 1 < nk) {
      if constexpr (BN == 128) asm volatile("s_waitcnt vmcnt(4)");
      else asm volatile("s_waitcnt vmcnt(3)");
    } else {
      asm volatile("s_waitcnt vmcnt(0)");
    }
    __syncthreads();

    const char* Ac = (const char*)&As[kt % 3][0];
    const char* Bc = (const char*)&Bs[kt % 3][0];
    short8 af[FM], bfr[FN];
#pragma unroll
    for (int m = 0; m < FM; m++)
      af[m] = *(const short8*)(Ac + (wr * WM + m * 16 + q) * 64 + lsl);
#pragma unroll
    for (int n = 0; n < FN; n++)
      bfr[n] = *(const short8*)(Bc + (wc * 64 + n * 16 + q) * 64 + lsl);
#pragma unroll
    for (int m = 0; m < FM; m++)
#pragma unroll
      for (int n = 0; n < FN; n++)
        acc[m][n] =
            __builtin_amdgcn_mfma_f32_16x16x32_bf16(af[m], bfr[n], acc[m][n], 0, 0, 0);
    __syncthreads();
  }

#pragma unroll
  for (int n = 0; n < FN; n++) {
    const int col = col0 + wc * 64 + n * 16 + q;
    const float bv = bias[col];
#pragma unroll
    for (int m = 0; m < FM; m++) {
      const int rowb = row0 + wr * WM + m * 16 + g * 4;
#pragma unroll
      for (int r = 0; r < 4; r++) {
        const size_t idx = (size_t)(rowb + r) * N + col;
        const float v = acc[m][n][r] + bv;
        if (EPI == 0) {
          outb[idx] = f2bf(v);
        } else {
          const float t = tanhf(0.7978845608028654f * (v + 0.044715f * v * v * v));
          outb[idx] = f2bf(0.5f * v * (1.0f + t));
        }
      }
    }
  }
}

// ---------------- GEMM 64x64 (thin-N shapes): grid doubles to 768 blocks
// (3/CU) and 24KB LDS lets 4 blocks co-reside -> ~4x waves/CU vs the 128x64
// tile (R13: grid-limited at 14% occ). 4 waves in 2x2, each 32x32 output.
// EPI 1 only: +bias+resid -> f32. Same depth-3 pipeline + swizzles.
__global__ __launch_bounds__(256, 4) void kgemm64(
    const bf16* __restrict__ A, const bf16* __restrict__ BT,
    const float* __restrict__ bias, const float* __restrict__ resid,
    float* __restrict__ outf, int M, int N, int K, int NXB) {
  __shared__ bf16 As[3][64 * 32];
  __shared__ bf16 Bs[3][64 * 32];
  const int tid = threadIdx.x;
  const int wid = tid >> 6, lane = tid & 63, g = lane >> 4, q = lane & 15;
  const int wr = wid >> 1, wc = wid & 1;

  const int bid = blockIdx.x;
  const int lb = (bid & 7) * ((int)gridDim.x >> 3) + (bid >> 3);
  const int row0 = (lb / NXB) * 64, col0 = (lb % NXB) * 64;

  floatx4 acc[2][2] = {};
  const int r0 = tid >> 2;                               // 0..63
  const int c0 = (((tid & 3) ^ ((r0 >> 1) & 3))) * 8;    // pre-swizzled src col
  const int lsl = (g ^ ((q >> 1) & 3)) * 16;             // reader slot (bytes)
  const bf16* Ab = A + (size_t)row0 * K;
  const bf16* Bb = BT + (size_t)col0 * K;

  auto STAGE = [&](int kk, int buf) {
    GLDS16(Ab + (size_t)r0 * K + kk + c0, (char*)&As[buf][0] + wid * 1024);
    GLDS16(Bb + (size_t)r0 * K + kk + c0, (char*)&Bs[buf][0] + wid * 1024);
  };

  const int nk = K >> 5;
  STAGE(0, 0);
  STAGE(32, 1);

  for (int kt = 0; kt < nk; kt++) {
    if (kt + 2 < nk) {
      STAGE((kt + 2) << 5, (kt + 2) % 3);
      asm volatile("s_waitcnt vmcnt(4)");
    } else if (kt + 1 < nk) {
      asm volatile("s_waitcnt vmcnt(2)");
    } else {
      asm volatile("s_waitcnt vmcnt(0)");
    }
    __syncthreads();

    const char* Ac = (const char*)&As[kt % 3][0];
    const char* Bc = (const char*)&Bs[kt % 3][0];
    short8 af[2], bfr[2];
#pragma unroll
    for (int m = 0; m < 2; m++)
      af[m] = *(const short8*)(Ac + (wr * 32 + m * 16 + q) * 64 + lsl);
#pragma unroll
    for (int n = 0; n < 2; n++)
      bfr[n] = *(const short8*)(Bc + (wc * 32 + n * 16 + q) * 64 + lsl);
#pragma unroll
    for (int m = 0; m < 2; m++)
#pragma unroll
      for (int n = 0; n < 2; n++)
        acc[m][n] =
            __builtin_amdgcn_mfma_f32_16x16x32_bf16(af[m], bfr[n], acc[m][n], 0, 0, 0);
    __syncthreads();
  }

#pragma unroll
  for (int n = 0; n < 2; n++) {
    const int col = col0 + wc * 32 + n * 16 + q;
    const float bv = bias[col];
#pragma unroll
    for (int m = 0; m < 2; m++) {
      const int rowb = row0 + wr * 32 + m * 16 + g * 4;
#pragma unroll
      for (int r = 0; r < 4; r++) {
        const size_t idx = (size_t)(rowb + r) * N + col;
        outf[idx] = acc[m][n][r] + bv + resid[idx];
      }
    }
  }
}

// ---------------- causal flash attention v9 (unchanged — verified)
__global__ __launch_bounds__(256, 2) void kattn(const bf16* __restrict__ qkv,
                                                const bf16* __restrict__ VT,
                                                bf16* __restrict__ y) {
  const int T = 2048, C3 = 2304;
  const int tid = threadIdx.x;
  const int w = tid >> 6, lane = tid & 63;
  const int g = lane >> 4, qi = lane & 15;

  const int bid = blockIdx.x;
  const int lb = (bid & 7) * 96 + (bid >> 3);
  const int qblk = 31 - (lb & 31);
  const int h = (lb >> 5) % 12, b = (lb >> 5) / 12;
  const int q0w = qblk * 64 + w * 16;
  const int qrow = q0w + qi;

  const bf16* Qb = qkv + (size_t)b * T * C3 + h * 64;
  const char* Ksrc = (const char*)(Qb + 768);
  const char* Vsrc = (const char*)(VT + (size_t)(b * 12 + h) * 64 * T);

  __shared__ __align__(16) char smem[32768];

  const int nt = qblk + 1;

  short8 qf[2];
#pragma unroll
  for (int s = 0; s < 2; s++)
    qf[s] = *(const short8*)(Qb + (size_t)qrow * C3 + s * 32 + g * 8);

  const int kvb = (qi >> 2) * 8 + (qi & 3);
  const unsigned swz = (unsigned)(((lane & 7) ^ (lane >> 3)) << 4);
  const int srow = lane >> 3;

  float m_run = -1e30f, l_run = 0.f;
  floatx4 o[4] = {};

#define STAGE(t)                                                                   \
  {                                                                                \
    char* base_ = smem + ((t) & 1) * 16384;                                        \
    const int kv0_ = (t) * 64;                                                     \
    _Pragma("unroll")                                                              \
    for (int j = 0; j < 2; j++) {                                                  \
      const int c_ = w * 2 + j;                                                    \
      GLDS16(Ksrc + (size_t)(kv0_ + c_ * 8 + srow) * 4608 + swz, base_ + c_ * 1024); \
      GLDS16(Vsrc + (size_t)(c_ * 8 + srow) * 4096 + kv0_ * 2 + swz,               \
             base_ + 8192 + c_ * 1024);                                            \
    }                                                                              \
  }

  STAGE(0);
  asm volatile("s_waitcnt vmcnt(0)");
  __syncthreads();

  for (int t = 0; t < nt; t++) {
    if (t + 1 < nt) STAGE(t + 1);
    const char* Kl = smem + (t & 1) * 16384;
    const char* Vl = Kl + 8192;
    const int kv0 = t * 64;

    short8 kf[8];
#pragma unroll
    for (int c = 0; c < 4; c++) {
      const int R = kvb + (c & 1) * 4 + (c >> 1) * 32;
#pragma unroll
      for (int s = 0; s < 2; s++)
        kf[c * 2 + s] =
            *(const short8*)(Kl + R * 128 + (((s * 4 + g) ^ (R & 7)) << 4));
    }
    short8 vfr[8];
#pragma unroll
    for (int ks = 0; ks < 2; ks++)
#pragma unroll
      for (int n = 0; n < 4; n++) {
        const int R2 = n * 16 + qi;
        vfr[ks * 4 + n] =
            *(const short8*)(Vl + R2 * 128 + (((ks * 4 + g) ^ (R2 & 7)) << 4));
      }

    floatx4 sacc[4] = {};
#pragma unroll
    for (int c = 0; c < 4; c++)
#pragma unroll
      for (int s = 0; s < 2; s++)
        sacc[c] =
            __builtin_amdgcn_mfma_f32_16x16x32_bf16(kf[c * 2 + s], qf[s], sacc[c], 0, 0, 0);

    if (kv0 + 63 > q0w) {
#pragma unroll
      for (int c = 0; c < 4; c++)
#pragma unroll
        for (int r = 0; r < 4; r++) {
          const int kv = kv0 + g * 8 + (c & 1) * 4 + r + (c >> 1) * 32;
          if (kv > qrow) sacc[c][r] = -1e30f;
        }
    }
    float mx = sacc[0][0];
#pragma unroll
    for (int c = 0; c < 4; c++)
#pragma unroll
      for (int r = 0; r < 4; r++) mx = fmaxf(mx, sacc[c][r]);
    mx = fmaxf(mx, __shfl_xor(mx, 16));
    mx = fmaxf(mx, __shfl_xor(mx, 32));
    mx *= 0.125f;
    const float mn = fmaxf(m_run, mx);
    const float al = __expf(m_run - mn);
    float ps = 0.f;
    unsigned pk[8];
#pragma unroll
    for (int c = 0; c < 4; c++) {
      float p0 = __expf(fmaf(sacc[c][0], 0.125f, -mn));
      float p1 = __expf(fmaf(sacc[c][1], 0.125f, -mn));
      float p2 = __expf(fmaf(sacc[c][2], 0.125f, -mn));
      float p3 = __expf(fmaf(sacc[c][3], 0.125f, -mn));
      ps += (p0 + p1) + (p2 + p3);
      pk[c * 2] = cvtpk(p0, p1);
      pk[c * 2 + 1] = cvtpk(p2, p3);
    }
    ps += __shfl_xor(ps, 16);
    ps += __shfl_xor(ps, 32);
    l_run = l_run * al + ps;
    m_run = mn;
#pragma unroll
    for (int n = 0; n < 4; n++) o[n] *= al;

#pragma unroll
    for (int ks = 0; ks < 2; ks++) {
      uintx4 pu;
      pu.x = pk[ks * 4 + 0];
      pu.y = pk[ks * 4 + 1];
      pu.z = pk[ks * 4 + 2];
      pu.w = pk[ks * 4 + 3];
      const short8 pf = __builtin_bit_cast(short8, pu);
#pragma unroll
      for (int n = 0; n < 4; n++)
        o[n] = __builtin_amdgcn_mfma_f32_16x16x32_bf16(vfr[ks * 4 + n], pf, o[n], 0, 0, 0);
    }

    asm volatile("s_waitcnt vmcnt(0)");
    __syncthreads();
  }
#undef STAGE

  const float inv = 1.0f / l_run;
  bf16* yr = y + (size_t)(b * T + qrow) * 768 + h * 64;
#pragma unroll
  for (int n = 0; n < 4; n++) {
    uint2 pr;
    pr.x = cvtpk(o[n][0] * inv, o[n][1] * inv);
    pr.y = cvtpk(o[n][2] * inv, o[n][3] * inv);
    *(uint2*)(yr + n * 16 + g * 4) = pr;
  }
}

// ---------------- host side
extern "C" void kernel_launch(void* const* d_in, const int* in_sizes, int n_in,
                              void* d_out, int out_size, void* d_ws, size_t ws_size,
                              hipStream_t stream) {
  const float* x      = (const float*)d_in[0];
  const float* ln1_g  = (const float*)d_in[1];
  const float* ln1_b  = (const float*)d_in[2];
  const float* w_attn = (const float*)d_in[3];
  const float* b_attn = (const float*)d_in[4];
  const float* w_proj = (const float*)d_in[5];
  const float* b_proj = (const float*)d_in[6];
  const float* ln2_g  = (const float*)d_in[7];
  const float* ln2_b  = (const float*)d_in[8];
  const float* w_fc   = (const float*)d_in[9];
  const float* b_fc   = (const float*)d_in[10];
  const float* w_fc2  = (const float*)d_in[11];
  const float* b_fc2  = (const float*)d_in[12];
  float* out = (float*)d_out;

  const int M = 4096;  // B*T
  char* p = (char*)d_ws;
  bf16* wT_attn = (bf16*)p; p += (size_t)2304 * 768 * 2;
  bf16* wT_proj = (bf16*)p; p += (size_t)768 * 768 * 2;
  bf16* wT_fc   = (bf16*)p; p += (size_t)3072 * 768 * 2;
  bf16* wT_fc2  = (bf16*)p; p += (size_t)768 * 3072 * 2;
  bf16* h       = (bf16*)p; p += (size_t)M * 768 * 2;
  bf16* qkv     = (bf16*)p;
  bf16* yb      = (bf16*)(p + (size_t)M * 2304 * 2);
  bf16* act     = qkv;      p += (size_t)M * 2304 * 2 + (size_t)M * 768 * 2;
  float* x1     = (float*)p;
  bf16* VT      = (bf16*)p;  // aliases x1: VT dead before x1 is written

  // weights -> bf16 transposed
  kconvT<<<dim3(2304 / 32, 768 / 32), 256, 0, stream>>>(w_attn, wT_attn, 768, 2304);
  kconvT<<<dim3(768 / 32, 768 / 32), 256, 0, stream>>>(w_proj, wT_proj, 768, 768);
  kconvT<<<dim3(3072 / 32, 768 / 32), 256, 0, stream>>>(w_fc, wT_fc, 768, 3072);
  kconvT<<<dim3(768 / 32, 3072 / 32), 256, 0, stream>>>(w_fc2, wT_fc2, 3072, 768);

  // attention branch
  kln<<<M, 256, 0, stream>>>(x, ln1_g, ln1_b, h);
  kgemm<128, 0><<<dim3(18 * 32), 256, 0, stream>>>(
      h, wT_attn, b_attn, nullptr, qkv, nullptr, M, 2304, 768, 18);
  kxpose<<<dim3(32, 12, 2), 256, 0, stream>>>(qkv, VT);
  kattn<<<dim3(768), 256, 0, stream>>>(qkv, VT, yb);
  kgemm64<<<dim3(64 * 12), 256, 0, stream>>>(
      yb, wT_proj, b_proj, x, x1, M, 768, 768, 12);

  // MLP branch
  kln<<<M, 256, 0, stream>>>(x1, ln2_g, ln2_b, h);
  kgemm<128, 2><<<dim3(24 * 32), 256, 0, stream>>>(
      h, wT_fc, b_fc, nullptr, act, nullptr, M, 3072, 768, 24);
  kgemm64<<<dim3(64 * 12), 256, 0, stream>>>(
      act, wT_fc2, b_fc2, x1, out, M, 768, 3072, 12);
}

// Round 16
// 192.947 us; speedup vs baseline: 1.2813x; 1.0834x over previous
//
#include <hip/hip_runtime.h>
#include <hip/hip_bf16.h>
#include <math.h>

typedef __hip_bfloat16 bf16;
typedef __attribute__((ext_vector_type(8))) short short8;
typedef __attribute__((ext_vector_type(4))) float floatx4;
typedef __attribute__((ext_vector_type(4))) unsigned uintx4;

#define GLDS16(g, l) __builtin_amdgcn_global_load_lds( \
    (const __attribute__((address_space(1))) void*)(g), \
    (__attribute__((address_space(3))) void*)(l), 16, 0, 0)

__device__ __forceinline__ bf16 f2bf(float v) { return __float2bfloat16(v); }

__device__ __forceinline__ unsigned cvtpk(float a, float b) {
  unsigned r;
  asm volatile("v_cvt_pk_bf16_f32 %0, %1, %2" : "=v"(r) : "v"(a), "v"(b));
  return r;
}

// ---------------- weight convert + transpose: w[K][N] f32 -> wT[N][K] bf16
__global__ __launch_bounds__(256) void kconvT(const float* __restrict__ w,
                                              bf16* __restrict__ wT,
                                              int K, int N) {
  __shared__ float tile[32][33];
  const int n0 = blockIdx.x * 32, k0 = blockIdx.y * 32;
  const int tc = threadIdx.x & 31, tr = threadIdx.x >> 5;
#pragma unroll
  for (int p = 0; p < 4; p++)
    tile[tr + p * 8][tc] = w[(size_t)(k0 + tr + p * 8) * N + n0 + tc];
  __syncthreads();
#pragma unroll
  for (int p = 0; p < 4; p++)
    wT[(size_t)(n0 + tr + p * 8) * K + k0 + tc] = f2bf(tile[tc][tr + p * 8]);
}

// ---------------- LayerNorm: f32 [rows][768] -> bf16
__global__ __launch_bounds__(256) void kln(const float* __restrict__ x,
                                           const float* __restrict__ gw,
                                           const float* __restrict__ bw,
                                           bf16* __restrict__ out) {
  const int row = blockIdx.x, tid = threadIdx.x;
  const float* xr = x + (size_t)row * 768;
  float v0 = xr[tid], v1 = xr[tid + 256], v2 = xr[tid + 512];
  float s = v0 + v1 + v2;
  float s2 = v0 * v0 + v1 * v1 + v2 * v2;
#pragma unroll
  for (int off = 1; off < 64; off <<= 1) {
    s += __shfl_xor(s, off);
    s2 += __shfl_xor(s2, off);
  }
  __shared__ float red[8];
  const int wid = tid >> 6, lane = tid & 63;
  if (lane == 0) { red[wid] = s; red[4 + wid] = s2; }
  __syncthreads();
  s = red[0] + red[1] + red[2] + red[3];
  s2 = red[4] + red[5] + red[6] + red[7];
  const float mu = s * (1.f / 768.f);
  const float rst = rsqrtf(fmaxf(s2 * (1.f / 768.f) - mu * mu, 0.f) + 1e-5f);
  bf16* orow = out + (size_t)row * 768;
  orow[tid] = f2bf((v0 - mu) * rst * gw[tid] + bw[tid]);
  orow[tid + 256] = f2bf((v1 - mu) * rst * gw[tid + 256] + bw[tid + 256]);
  orow[tid + 512] = f2bf((v2 - mu) * rst * gw[tid + 512] + bw[tid + 512]);
}

// ---------------- V transpose: qkv[b*T+t][1536 + h*64 + d] -> VT[b][h][d][t]
__global__ __launch_bounds__(256) void kxpose(const bf16* __restrict__ qkv,
                                              bf16* __restrict__ VT) {
  const int T = 2048, C3 = 2304;
  const int t0 = blockIdx.x * 64, h = blockIdx.y, b = blockIdx.z;
  const int tid = threadIdx.x;
  __shared__ short tile[64][66];
  const bf16* src = qkv + (size_t)b * T * C3 + 1536 + h * 64;
  const int tr = tid >> 3, c = tid & 7;
#pragma unroll
  for (int p = 0; p < 2; p++) {
    short8 v = *(const short8*)(src + (size_t)(t0 + tr + p * 32) * C3 + c * 8);
    *(short8*)&tile[tr + p * 32][c * 8] = v;
  }
  __syncthreads();
  bf16* dst = VT + ((size_t)(b * 12 + h) * 64) * T + t0;
#pragma unroll
  for (int p = 0; p < 2; p++) {
    const int d = (tid >> 3) + p * 32, tc = tid & 7;
    short8 v;
#pragma unroll
    for (int j = 0; j < 8; j++) v[j] = tile[tc * 8 + j][d];
    *(short8*)(dst + (size_t)d * T + tc * 8) = v;
  }
}

// ---------------- GEMM v3 (BM=128): depth-3 pipeline, counted vmcnt,
// XCD-chunked swizzle, XOR bank swizzle. EPI 0: +bias->bf16  EPI 2: GELU->bf16
template <int BN, int EPI>
__global__ __launch_bounds__(256, 2) void kgemm(
    const bf16* __restrict__ A, const bf16* __restrict__ BT,
    const float* __restrict__ bias, const float* __restrict__ resid,
    bf16* __restrict__ outb, float* __restrict__ outf, int M, int N, int K,
    int NXB) {
  __shared__ bf16 As[3][128 * 32];
  __shared__ bf16 Bs[3][BN * 32];
  const int tid = threadIdx.x;
  const int wid = tid >> 6, lane = tid & 63, g = lane >> 4, q = lane & 15;
  constexpr int FM = (BN == 128) ? 4 : 2;
  constexpr int FN = 4;
  constexpr int WM = (BN == 128) ? 64 : 32;
  const int wr = (BN == 128) ? (wid >> 1) : wid;
  const int wc = (BN == 128) ? (wid & 1) : 0;

  const int bid = blockIdx.x;
  const int lb = (bid & 7) * ((int)gridDim.x >> 3) + (bid >> 3);
  const int row0 = (lb / NXB) * 128, col0 = (lb % NXB) * BN;

  floatx4 acc[FM][FN] = {};
  const int r0 = tid >> 2;
  const int c0 = (((tid & 3) ^ ((r0 >> 1) & 3))) * 8;
  const int lsl = (g ^ ((q >> 1) & 3)) * 16;
  const bf16* Ab = A + (size_t)row0 * K;
  const bf16* Bb = BT + (size_t)col0 * K;

  auto STAGE = [&](int kk, int buf) {
    GLDS16(Ab + (size_t)r0 * K + kk + c0, (char*)&As[buf][0] + wid * 1024);
    GLDS16(Ab + (size_t)(r0 + 64) * K + kk + c0,
           (char*)&As[buf][0] + 4096 + wid * 1024);
    GLDS16(Bb + (size_t)r0 * K + kk + c0, (char*)&Bs[buf][0] + wid * 1024);
    if constexpr (BN == 128)
      GLDS16(Bb + (size_t)(r0 + 64) * K + kk + c0,
             (char*)&Bs[buf][0] + 4096 + wid * 1024);
  };

  const int nk = K >> 5;
  STAGE(0, 0);
  STAGE(32, 1);

  for (int kt = 0; kt < nk; kt++) {
    if (kt + 2 < nk) {
      STAGE((kt + 2) << 5, (kt + 2) % 3);
      if constexpr (BN == 128) asm volatile("s_waitcnt vmcnt(8)");
      else asm volatile("s_waitcnt vmcnt(6)");
    } else if (kt + 1 < nk) {
      if constexpr (BN == 128) asm volatile("s_waitcnt vmcnt(4)");
      else asm volatile("s_waitcnt vmcnt(3)");
    } else {
      asm volatile("s_waitcnt vmcnt(0)");
    }
    __syncthreads();

    const char* Ac = (const char*)&As[kt % 3][0];
    const char* Bc = (const char*)&Bs[kt % 3][0];
    short8 af[FM], bfr[FN];
#pragma unroll
    for (int m = 0; m < FM; m++)
      af[m] = *(const short8*)(Ac + (wr * WM + m * 16 + q) * 64 + lsl);
#pragma unroll
    for (int n = 0; n < FN; n++)
      bfr[n] = *(const short8*)(Bc + (wc * 64 + n * 16 + q) * 64 + lsl);
#pragma unroll
    for (int m = 0; m < FM; m++)
#pragma unroll
      for (int n = 0; n < FN; n++)
        acc[m][n] =
            __builtin_amdgcn_mfma_f32_16x16x32_bf16(af[m], bfr[n], acc[m][n], 0, 0, 0);
    __syncthreads();
  }

#pragma unroll
  for (int n = 0; n < FN; n++) {
    const int col = col0 + wc * 64 + n * 16 + q;
    const float bv = bias[col];
#pragma unroll
    for (int m = 0; m < FM; m++) {
      const int rowb = row0 + wr * WM + m * 16 + g * 4;
#pragma unroll
      for (int r = 0; r < 4; r++) {
        const size_t idx = (size_t)(rowb + r) * N + col;
        const float v = acc[m][n][r] + bv;
        if (EPI == 0) {
          outb[idx] = f2bf(v);
        } else {
          const float t = tanhf(0.7978845608028654f * (v + 0.044715f * v * v * v));
          outb[idx] = f2bf(0.5f * v * (1.0f + t));
        }
      }
    }
  }
}

// ---------------- GEMM 64x64 v4: BK=64, ONE barrier per K-step, depth-3.
// R15: halving the tile doubled occupancy but fc2 stayed 55us -> bound by
// per-K-step serial cost x step count (96 steps x ~1350cy), not wave supply.
// Now: BK=64 halves steps (8 MFMA/step), and with 3 buffers the top barrier
// alone protects stage-visibility AND buffer-overwrite (STAGE(kt+2) hits
// buf (kt-1)%3, last read before the barrier just passed). Staging/swizzle
// pattern copied from kattn's verified K-tile stager (128B rows, XOR row&7).
// EPI: +bias+resid -> f32.
__global__ __launch_bounds__(256, 3) void kgemm64(
    const bf16* __restrict__ A, const bf16* __restrict__ BT,
    const float* __restrict__ bias, const float* __restrict__ resid,
    float* __restrict__ outf, int M, int N, int K, int NXB) {
  __shared__ bf16 As[3][64 * 64];  // 8KB per buffer
  __shared__ bf16 Bs[3][64 * 64];
  const int tid = threadIdx.x;
  const int wid = tid >> 6, lane = tid & 63, g = lane >> 4, q = lane & 15;
  const int wr = wid >> 1, wc = wid & 1;

  const int bid = blockIdx.x;
  const int lb = (bid & 7) * ((int)gridDim.x >> 3) + (bid >> 3);
  const int row0 = (lb / NXB) * 64, col0 = (lb % NXB) * 64;

  floatx4 acc[2][2] = {};
  const int srow = lane >> 3;                       // 0..7
  const unsigned swz = ((lane & 7) ^ srow) << 4;    // pre-swizzled src slot
  const char* Ab = (const char*)(A + (size_t)row0 * K);
  const char* Bb = (const char*)(BT + (size_t)col0 * K);
  const size_t Kb2 = (size_t)K * 2;

  // stage one 64x64 tile pair; each wave stages rows wid*16..wid*16+15 of each
  auto STAGE = [&](int kk, int buf) {
#pragma unroll
    for (int j = 0; j < 2; j++) {
      const int rA = wid * 16 + j * 8;
      GLDS16(Ab + (size_t)(rA + srow) * Kb2 + kk * 2 + swz,
             (char*)&As[buf][0] + rA * 128);
      GLDS16(Bb + (size_t)(rA + srow) * Kb2 + kk * 2 + swz,
             (char*)&Bs[buf][0] + rA * 128);
    }
  };

  const int nk = K >> 6;
  STAGE(0, 0);
  STAGE(64, 1);

  for (int kt = 0; kt < nk; kt++) {
    if (kt + 1 < nk) asm volatile("s_waitcnt vmcnt(4)");
    else asm volatile("s_waitcnt vmcnt(0)");
    __syncthreads();
    if (kt + 2 < nk) STAGE((kt + 2) << 6, (kt + 2) % 3);

    const char* Ac = (const char*)&As[kt % 3][0];
    const char* Bc = (const char*)&Bs[kt % 3][0];
    short8 af[2][2], bfr[2][2];
#pragma unroll
    for (int m = 0; m < 2; m++) {
      const int R = wr * 32 + m * 16 + q;
#pragma unroll
      for (int s = 0; s < 2; s++)
        af[m][s] = *(const short8*)(Ac + R * 128 + (((s * 4 + g) ^ (R & 7)) << 4));
    }
#pragma unroll
    for (int n = 0; n < 2; n++) {
      const int R = wc * 32 + n * 16 + q;
#pragma unroll
      for (int s = 0; s < 2; s++)
        bfr[n][s] = *(const short8*)(Bc + R * 128 + (((s * 4 + g) ^ (R & 7)) << 4));
    }
#pragma unroll
    for (int m = 0; m < 2; m++)
#pragma unroll
      for (int n = 0; n < 2; n++)
#pragma unroll
        for (int s = 0; s < 2; s++)
          acc[m][n] = __builtin_amdgcn_mfma_f32_16x16x32_bf16(af[m][s], bfr[n][s],
                                                              acc[m][n], 0, 0, 0);
  }

#pragma unroll
  for (int n = 0; n < 2; n++) {
    const int col = col0 + wc * 32 + n * 16 + q;
    const float bv = bias[col];
#pragma unroll
    for (int m = 0; m < 2; m++) {
      const int rowb = row0 + wr * 32 + m * 16 + g * 4;
#pragma unroll
      for (int r = 0; r < 4; r++) {
        const size_t idx = (size_t)(rowb + r) * N + col;
        outf[idx] = acc[m][n][r] + bv + resid[idx];
      }
    }
  }
}

// ---------------- causal flash attention v9 (unchanged — verified)
__global__ __launch_bounds__(256, 2) void kattn(const bf16* __restrict__ qkv,
                                                const bf16* __restrict__ VT,
                                                bf16* __restrict__ y) {
  const int T = 2048, C3 = 2304;
  const int tid = threadIdx.x;
  const int w = tid >> 6, lane = tid & 63;
  const int g = lane >> 4, qi = lane & 15;

  const int bid = blockIdx.x;
  const int lb = (bid & 7) * 96 + (bid >> 3);
  const int qblk = 31 - (lb & 31);
  const int h = (lb >> 5) % 12, b = (lb >> 5) / 12;
  const int q0w = qblk * 64 + w * 16;
  const int qrow = q0w + qi;

  const bf16* Qb = qkv + (size_t)b * T * C3 + h * 64;
  const char* Ksrc = (const char*)(Qb + 768);
  const char* Vsrc = (const char*)(VT + (size_t)(b * 12 + h) * 64 * T);

  __shared__ __align__(16) char smem[32768];

  const int nt = qblk + 1;

  short8 qf[2];
#pragma unroll
  for (int s = 0; s < 2; s++)
    qf[s] = *(const short8*)(Qb + (size_t)qrow * C3 + s * 32 + g * 8);

  const int kvb = (qi >> 2) * 8 + (qi & 3);
  const unsigned swz = (unsigned)(((lane & 7) ^ (lane >> 3)) << 4);
  const int srow = lane >> 3;

  float m_run = -1e30f, l_run = 0.f;
  floatx4 o[4] = {};

#define STAGE(t)                                                                   \
  {                                                                                \
    char* base_ = smem + ((t) & 1) * 16384;                                        \
    const int kv0_ = (t) * 64;                                                     \
    _Pragma("unroll")                                                              \
    for (int j = 0; j < 2; j++) {                                                  \
      const int c_ = w * 2 + j;                                                    \
      GLDS16(Ksrc + (size_t)(kv0_ + c_ * 8 + srow) * 4608 + swz, base_ + c_ * 1024); \
      GLDS16(Vsrc + (size_t)(c_ * 8 + srow) * 4096 + kv0_ * 2 + swz,               \
             base_ + 8192 + c_ * 1024);                                            \
    }                                                                              \
  }

  STAGE(0);
  asm volatile("s_waitcnt vmcnt(0)");
  __syncthreads();

  for (int t = 0; t < nt; t++) {
    if (t + 1 < nt) STAGE(t + 1);
    const char* Kl = smem + (t & 1) * 16384;
    const char* Vl = Kl + 8192;
    const int kv0 = t * 64;

    short8 kf[8];
#pragma unroll
    for (int c = 0; c < 4; c++) {
      const int R = kvb + (c & 1) * 4 + (c >> 1) * 32;
#pragma unroll
      for (int s = 0; s < 2; s++)
        kf[c * 2 + s] =
            *(const short8*)(Kl + R * 128 + (((s * 4 + g) ^ (R & 7)) << 4));
    }
    short8 vfr[8];
#pragma unroll
    for (int ks = 0; ks < 2; ks++)
#pragma unroll
      for (int n = 0; n < 4; n++) {
        const int R2 = n * 16 + qi;
        vfr[ks * 4 + n] =
            *(const short8*)(Vl + R2 * 128 + (((ks * 4 + g) ^ (R2 & 7)) << 4));
      }

    floatx4 sacc[4] = {};
#pragma unroll
    for (int c = 0; c < 4; c++)
#pragma unroll
      for (int s = 0; s < 2; s++)
        sacc[c] =
            __builtin_amdgcn_mfma_f32_16x16x32_bf16(kf[c * 2 + s], qf[s], sacc[c], 0, 0, 0);

    if (kv0 + 63 > q0w) {
#pragma unroll
      for (int c = 0; c < 4; c++)
#pragma unroll
        for (int r = 0; r < 4; r++) {
          const int kv = kv0 + g * 8 + (c & 1) * 4 + r + (c >> 1) * 32;
          if (kv > qrow) sacc[c][r] = -1e30f;
        }
    }
    float mx = sacc[0][0];
#pragma unroll
    for (int c = 0; c < 4; c++)
#pragma unroll
      for (int r = 0; r < 4; r++) mx = fmaxf(mx, sacc[c][r]);
    mx = fmaxf(mx, __shfl_xor(mx, 16));
    mx = fmaxf(mx, __shfl_xor(mx, 32));
    mx *= 0.125f;
    const float mn = fmaxf(m_run, mx);
    const float al = __expf(m_run - mn);
    float ps = 0.f;
    unsigned pk[8];
#pragma unroll
    for (int c = 0; c < 4; c++) {
      float p0 = __expf(fmaf(sacc[c][0], 0.125f, -mn));
      float p1 = __expf(fmaf(sacc[c][1], 0.125f, -mn));
      float p2 = __expf(fmaf(sacc[c][2], 0.125f, -mn));
      float p3 = __expf(fmaf(sacc[c][3], 0.125f, -mn));
      ps += (p0 + p1) + (p2 + p3);
      pk[c * 2] = cvtpk(p0, p1);
      pk[c * 2 + 1] = cvtpk(p2, p3);
    }
    ps += __shfl_xor(ps, 16);
    ps += __shfl_xor(ps, 32);
    l_run = l_run * al + ps;
    m_run = mn;
#pragma unroll
    for (int n = 0; n < 4; n++) o[n] *= al;

#pragma unroll
    for (int ks = 0; ks < 2; ks++) {
      uintx4 pu;
      pu.x = pk[ks * 4 + 0];
      pu.y = pk[ks * 4 + 1];
      pu.z = pk[ks * 4 + 2];
      pu.w = pk[ks * 4 + 3];
      const short8 pf = __builtin_bit_cast(short8, pu);
#pragma unroll
      for (int n = 0; n < 4; n++)
        o[n] = __builtin_amdgcn_mfma_f32_16x16x32_bf16(vfr[ks * 4 + n], pf, o[n], 0, 0, 0);
    }

    asm volatile("s_waitcnt vmcnt(0)");
    __syncthreads();
  }
#undef STAGE

  const float inv = 1.0f / l_run;
  bf16* yr = y + (size_t)(b * T + qrow) * 768 + h * 64;
#pragma unroll
  for (int n = 0; n < 4; n++) {
    uint2 pr;
    pr.x = cvtpk(o[n][0] * inv, o[n][1] * inv);
    pr.y = cvtpk(o[n][2] * inv, o[n][3] * inv);
    *(uint2*)(yr + n * 16 + g * 4) = pr;
  }
}

// ---------------- host side
extern "C" void kernel_launch(void* const* d_in, const int* in_sizes, int n_in,
                              void* d_out, int out_size, void* d_ws, size_t ws_size,
                              hipStream_t stream) {
  const float* x      = (const float*)d_in[0];
  const float* ln1_g  = (const float*)d_in[1];
  const float* ln1_b  = (const float*)d_in[2];
  const float* w_attn = (const float*)d_in[3];
  const float* b_attn = (const float*)d_in[4];
  const float* w_proj = (const float*)d_in[5];
  const float* b_proj = (const float*)d_in[6];
  const float* ln2_g  = (const float*)d_in[7];
  const float* ln2_b  = (const float*)d_in[8];
  const float* w_fc   = (const float*)d_in[9];
  const float* b_fc   = (const float*)d_in[10];
  const float* w_fc2  = (const float*)d_in[11];
  const float* b_fc2  = (const float*)d_in[12];
  float* out = (float*)d_out;

  const int M = 4096;  // B*T
  char* p = (char*)d_ws;
  bf16* wT_attn = (bf16*)p; p += (size_t)2304 * 768 * 2;
  bf16* wT_proj = (bf16*)p; p += (size_t)768 * 768 * 2;
  bf16* wT_fc   = (bf16*)p; p += (size_t)3072 * 768 * 2;
  bf16* wT_fc2  = (bf16*)p; p += (size_t)768 * 3072 * 2;
  bf16* h       = (bf16*)p; p += (size_t)M * 768 * 2;
  bf16* qkv     = (bf16*)p;
  bf16* yb      = (bf16*)(p + (size_t)M * 2304 * 2);
  bf16* act     = qkv;      p += (size_t)M * 2304 * 2 + (size_t)M * 768 * 2;
  float* x1     = (float*)p;
  bf16* VT      = (bf16*)p;  // aliases x1: VT dead before x1 is written

  // weights -> bf16 transposed
  kconvT<<<dim3(2304 / 32, 768 / 32), 256, 0, stream>>>(w_attn, wT_attn, 768, 2304);
  kconvT<<<dim3(768 / 32, 768 / 32), 256, 0, stream>>>(w_proj, wT_proj, 768, 768);
  kconvT<<<dim3(3072 / 32, 768 / 32), 256, 0, stream>>>(w_fc, wT_fc, 768, 3072);
  kconvT<<<dim3(768 / 32, 3072 / 32), 256, 0, stream>>>(w_fc2, wT_fc2, 3072, 768);

  // attention branch
  kln<<<M, 256, 0, stream>>>(x, ln1_g, ln1_b, h);
  kgemm<128, 0><<<dim3(18 * 32), 256, 0, stream>>>(
      h, wT_attn, b_attn, nullptr, qkv, nullptr, M, 2304, 768, 18);
  kxpose<<<dim3(32, 12, 2), 256, 0, stream>>>(qkv, VT);
  kattn<<<dim3(768), 256, 0, stream>>>(qkv, VT, yb);
  kgemm64<<<dim3(64 * 12), 256, 0, stream>>>(
      yb, wT_proj, b_proj, x, x1, M, 768, 768, 12);

  // MLP branch
  kln<<<M, 256, 0, stream>>>(x1, ln2_g, ln2_b, h);
  kgemm<128, 2><<<dim3(24 * 32), 256, 0, stream>>>(
      h, wT_fc, b_fc, nullptr, act, nullptr, M, 3072, 768, 24);
  kgemm64<<<dim3(64 * 12), 256, 0, stream>>>(
      act, wT_fc2, b_fc2, x1, out, M, 768, 3072, 12);
}

// Round 17
// 183.432 us; speedup vs baseline: 1.3478x; 1.0519x over previous
//
#include <hip/hip_runtime.h>
#include <hip/hip_bf16.h>
#include <math.h>

typedef __hip_bfloat16 bf16;
typedef __attribute__((ext_vector_type(8))) short short8;
typedef __attribute__((ext_vector_type(4))) float floatx4;
typedef __attribute__((ext_vector_type(4))) unsigned uintx4;

#define GLDS16(g, l) __builtin_amdgcn_global_load_lds( \
    (const __attribute__((address_space(1))) void*)(g), \
    (__attribute__((address_space(3))) void*)(l), 16, 0, 0)

__device__ __forceinline__ bf16 f2bf(float v) { return __float2bfloat16(v); }

__device__ __forceinline__ unsigned cvtpk(float a, float b) {
  unsigned r;
  asm volatile("v_cvt_pk_bf16_f32 %0, %1, %2" : "=v"(r) : "v"(a), "v"(b));
  return r;
}

// ---------------- weight convert + transpose: w[K][N] f32 -> wT[N][K] bf16
__global__ __launch_bounds__(256) void kconvT(const float* __restrict__ w,
                                              bf16* __restrict__ wT,
                                              int K, int N) {
  __shared__ float tile[32][33];
  const int n0 = blockIdx.x * 32, k0 = blockIdx.y * 32;
  const int tc = threadIdx.x & 31, tr = threadIdx.x >> 5;
#pragma unroll
  for (int p = 0; p < 4; p++)
    tile[tr + p * 8][tc] = w[(size_t)(k0 + tr + p * 8) * N + n0 + tc];
  __syncthreads();
#pragma unroll
  for (int p = 0; p < 4; p++)
    wT[(size_t)(n0 + tr + p * 8) * K + k0 + tc] = f2bf(tile[tc][tr + p * 8]);
}

// ---------------- LayerNorm: f32 [rows][768] -> bf16
__global__ __launch_bounds__(256) void kln(const float* __restrict__ x,
                                           const float* __restrict__ gw,
                                           const float* __restrict__ bw,
                                           bf16* __restrict__ out) {
  const int row = blockIdx.x, tid = threadIdx.x;
  const float* xr = x + (size_t)row * 768;
  float v0 = xr[tid], v1 = xr[tid + 256], v2 = xr[tid + 512];
  float s = v0 + v1 + v2;
  float s2 = v0 * v0 + v1 * v1 + v2 * v2;
#pragma unroll
  for (int off = 1; off < 64; off <<= 1) {
    s += __shfl_xor(s, off);
    s2 += __shfl_xor(s2, off);
  }
  __shared__ float red[8];
  const int wid = tid >> 6, lane = tid & 63;
  if (lane == 0) { red[wid] = s; red[4 + wid] = s2; }
  __syncthreads();
  s = red[0] + red[1] + red[2] + red[3];
  s2 = red[4] + red[5] + red[6] + red[7];
  const float mu = s * (1.f / 768.f);
  const float rst = rsqrtf(fmaxf(s2 * (1.f / 768.f) - mu * mu, 0.f) + 1e-5f);
  bf16* orow = out + (size_t)row * 768;
  orow[tid] = f2bf((v0 - mu) * rst * gw[tid] + bw[tid]);
  orow[tid + 256] = f2bf((v1 - mu) * rst * gw[tid + 256] + bw[tid + 256]);
  orow[tid + 512] = f2bf((v2 - mu) * rst * gw[tid + 512] + bw[tid + 512]);
}

// ---------------- V transpose: qkv[b*T+t][1536 + h*64 + d] -> VT[b][h][d][t]
__global__ __launch_bounds__(256) void kxpose(const bf16* __restrict__ qkv,
                                              bf16* __restrict__ VT) {
  const int T = 2048, C3 = 2304;
  const int t0 = blockIdx.x * 64, h = blockIdx.y, b = blockIdx.z;
  const int tid = threadIdx.x;
  __shared__ short tile[64][66];
  const bf16* src = qkv + (size_t)b * T * C3 + 1536 + h * 64;
  const int tr = tid >> 3, c = tid & 7;
#pragma unroll
  for (int p = 0; p < 2; p++) {
    short8 v = *(const short8*)(src + (size_t)(t0 + tr + p * 32) * C3 + c * 8);
    *(short8*)&tile[tr + p * 32][c * 8] = v;
  }
  __syncthreads();
  bf16* dst = VT + ((size_t)(b * 12 + h) * 64) * T + t0;
#pragma unroll
  for (int p = 0; p < 2; p++) {
    const int d = (tid >> 3) + p * 32, tc = tid & 7;
    short8 v;
#pragma unroll
    for (int j = 0; j < 8; j++) v[j] = tile[tc * 8 + j][d];
    *(short8*)(dst + (size_t)d * T + tc * 8) = v;
  }
}

// ---------------- GEMM v3 (BM=128): depth-3 pipeline, counted vmcnt,
// XCD-chunked swizzle, XOR bank swizzle. EPI 0: +bias->bf16  EPI 2: GELU->bf16
template <int BN, int EPI>
__global__ __launch_bounds__(256, 2) void kgemm(
    const bf16* __restrict__ A, const bf16* __restrict__ BT,
    const float* __restrict__ bias, const float* __restrict__ resid,
    bf16* __restrict__ outb, float* __restrict__ outf, int M, int N, int K,
    int NXB) {
  __shared__ bf16 As[3][128 * 32];
  __shared__ bf16 Bs[3][BN * 32];
  const int tid = threadIdx.x;
  const int wid = tid >> 6, lane = tid & 63, g = lane >> 4, q = lane & 15;
  constexpr int FM = (BN == 128) ? 4 : 2;
  constexpr int FN = 4;
  constexpr int WM = (BN == 128) ? 64 : 32;
  const int wr = (BN == 128) ? (wid >> 1) : wid;
  const int wc = (BN == 128) ? (wid & 1) : 0;

  const int bid = blockIdx.x;
  const int lb = (bid & 7) * ((int)gridDim.x >> 3) + (bid >> 3);
  const int row0 = (lb / NXB) * 128, col0 = (lb % NXB) * BN;

  floatx4 acc[FM][FN] = {};
  const int r0 = tid >> 2;
  const int c0 = (((tid & 3) ^ ((r0 >> 1) & 3))) * 8;
  const int lsl = (g ^ ((q >> 1) & 3)) * 16;
  const bf16* Ab = A + (size_t)row0 * K;
  const bf16* Bb = BT + (size_t)col0 * K;

  auto STAGE = [&](int kk, int buf) {
    GLDS16(Ab + (size_t)r0 * K + kk + c0, (char*)&As[buf][0] + wid * 1024);
    GLDS16(Ab + (size_t)(r0 + 64) * K + kk + c0,
           (char*)&As[buf][0] + 4096 + wid * 1024);
    GLDS16(Bb + (size_t)r0 * K + kk + c0, (char*)&Bs[buf][0] + wid * 1024);
    if constexpr (BN == 128)
      GLDS16(Bb + (size_t)(r0 + 64) * K + kk + c0,
             (char*)&Bs[buf][0] + 4096 + wid * 1024);
  };

  const int nk = K >> 5;
  STAGE(0, 0);
  STAGE(32, 1);

  for (int kt = 0; kt < nk; kt++) {
    if (kt + 2 < nk) {
      STAGE((kt + 2) << 5, (kt + 2) % 3);
      if constexpr (BN == 128) asm volatile("s_waitcnt vmcnt(8)");
      else asm volatile("s_waitcnt vmcnt(6)");
    } else if (kt + 1 < nk) {
      if constexpr (BN == 128) asm volatile("s_waitcnt vmcnt(4)");
      else asm volatile("s_waitcnt vmcnt(3)");
    } else {
      asm volatile("s_waitcnt vmcnt(0)");
    }
    __syncthreads();

    const char* Ac = (const char*)&As[kt % 3][0];
    const char* Bc = (const char*)&Bs[kt % 3][0];
    short8 af[FM], bfr[FN];
#pragma unroll
    for (int m = 0; m < FM; m++)
      af[m] = *(const short8*)(Ac + (wr * WM + m * 16 + q) * 64 + lsl);
#pragma unroll
    for (int n = 0; n < FN; n++)
      bfr[n] = *(const short8*)(Bc + (wc * 64 + n * 16 + q) * 64 + lsl);
#pragma unroll
    for (int m = 0; m < FM; m++)
#pragma unroll
      for (int n = 0; n < FN; n++)
        acc[m][n] =
            __builtin_amdgcn_mfma_f32_16x16x32_bf16(af[m], bfr[n], acc[m][n], 0, 0, 0);
    __syncthreads();
  }

#pragma unroll
  for (int n = 0; n < FN; n++) {
    const int col = col0 + wc * 64 + n * 16 + q;
    const float bv = bias[col];
#pragma unroll
    for (int m = 0; m < FM; m++) {
      const int rowb = row0 + wr * WM + m * 16 + g * 4;
#pragma unroll
      for (int r = 0; r < 4; r++) {
        const size_t idx = (size_t)(rowb + r) * N + col;
        const float v = acc[m][n][r] + bv;
        if (EPI == 0) {
          outb[idx] = f2bf(v);
        } else {
          const float t = tanhf(0.7978845608028654f * (v + 0.044715f * v * v * v));
          outb[idx] = f2bf(0.5f * v * (1.0f + t));
        }
      }
    }
  }
}

// ---------------- GEMM 64x64 v4: BK=64, ONE barrier per K-step, depth-3.
// (unchanged from R16 — verified; fc2 dropped out of top-5)
__global__ __launch_bounds__(256, 3) void kgemm64(
    const bf16* __restrict__ A, const bf16* __restrict__ BT,
    const float* __restrict__ bias, const float* __restrict__ resid,
    float* __restrict__ outf, int M, int N, int K, int NXB) {
  __shared__ bf16 As[3][64 * 64];
  __shared__ bf16 Bs[3][64 * 64];
  const int tid = threadIdx.x;
  const int wid = tid >> 6, lane = tid & 63, g = lane >> 4, q = lane & 15;
  const int wr = wid >> 1, wc = wid & 1;

  const int bid = blockIdx.x;
  const int lb = (bid & 7) * ((int)gridDim.x >> 3) + (bid >> 3);
  const int row0 = (lb / NXB) * 64, col0 = (lb % NXB) * 64;

  floatx4 acc[2][2] = {};
  const int srow = lane >> 3;
  const unsigned swz = ((lane & 7) ^ srow) << 4;
  const char* Ab = (const char*)(A + (size_t)row0 * K);
  const char* Bb = (const char*)(BT + (size_t)col0 * K);
  const size_t Kb2 = (size_t)K * 2;

  auto STAGE = [&](int kk, int buf) {
#pragma unroll
    for (int j = 0; j < 2; j++) {
      const int rA = wid * 16 + j * 8;
      GLDS16(Ab + (size_t)(rA + srow) * Kb2 + kk * 2 + swz,
             (char*)&As[buf][0] + rA * 128);
      GLDS16(Bb + (size_t)(rA + srow) * Kb2 + kk * 2 + swz,
             (char*)&Bs[buf][0] + rA * 128);
    }
  };

  const int nk = K >> 6;
  STAGE(0, 0);
  STAGE(64, 1);

  for (int kt = 0; kt < nk; kt++) {
    if (kt + 1 < nk) asm volatile("s_waitcnt vmcnt(4)");
    else asm volatile("s_waitcnt vmcnt(0)");
    __syncthreads();
    if (kt + 2 < nk) STAGE((kt + 2) << 6, (kt + 2) % 3);

    const char* Ac = (const char*)&As[kt % 3][0];
    const char* Bc = (const char*)&Bs[kt % 3][0];
    short8 af[2][2], bfr[2][2];
#pragma unroll
    for (int m = 0; m < 2; m++) {
      const int R = wr * 32 + m * 16 + q;
#pragma unroll
      for (int s = 0; s < 2; s++)
        af[m][s] = *(const short8*)(Ac + R * 128 + (((s * 4 + g) ^ (R & 7)) << 4));
    }
#pragma unroll
    for (int n = 0; n < 2; n++) {
      const int R = wc * 32 + n * 16 + q;
#pragma unroll
      for (int s = 0; s < 2; s++)
        bfr[n][s] = *(const short8*)(Bc + R * 128 + (((s * 4 + g) ^ (R & 7)) << 4));
    }
#pragma unroll
    for (int m = 0; m < 2; m++)
#pragma unroll
      for (int n = 0; n < 2; n++)
#pragma unroll
        for (int s = 0; s < 2; s++)
          acc[m][n] = __builtin_amdgcn_mfma_f32_16x16x32_bf16(af[m][s], bfr[n][s],
                                                              acc[m][n], 0, 0, 0);
  }

#pragma unroll
  for (int n = 0; n < 2; n++) {
    const int col = col0 + wc * 32 + n * 16 + q;
    const float bv = bias[col];
#pragma unroll
    for (int m = 0; m < 2; m++) {
      const int rowb = row0 + wr * 32 + m * 16 + g * 4;
#pragma unroll
      for (int r = 0; r < 4; r++) {
        const size_t idx = (size_t)(rowb + r) * N + col;
        outf[idx] = acc[m][n][r] + bv + resid[idx];
      }
    }
  }
}

// ---------------- causal flash attention v10:
// R16 diagnosis: K-reads 4-way bank-conflicted (slot^(R&7) collapses to 4
// values over 16 lanes -> 1.6M conflicts), per-tile vmcnt(0) drain, and
// co-resident blocks share qblk (makespan 96 vs 49.5 avg tiles).
// Fixes: (a) swizzle g(r)=(r&3)|(((r>>3)&1)<<2) -> K and V reads both 2-way
// (free); (b) 3-buffer staging, counted vmcnt(4) at tile top, one barrier,
// STAGE(t+2) after barrier (kgemm64's verified schedule); (c) parity qblk
// map (bh&1 ? i : 31-i) -> co-resident pair sums 33 tiles.
__global__ __launch_bounds__(256, 2) void kattn(const bf16* __restrict__ qkv,
                                                const bf16* __restrict__ VT,
                                                bf16* __restrict__ y) {
  const int T = 2048, C3 = 2304;
  const int tid = threadIdx.x;
  const int w = tid >> 6, lane = tid & 63;
  const int g = lane >> 4, qi = lane & 15;

  const int bid = blockIdx.x;
  const int lb = (bid & 7) * 96 + (bid >> 3);
  const int i = lb & 31, bh = lb >> 5;
  const int qblk = (bh & 1) ? i : 31 - i;
  const int h = bh % 12, b = bh / 12;
  const int q0w = qblk * 64 + w * 16;
  const int qrow = q0w + qi;

  const bf16* Qb = qkv + (size_t)b * T * C3 + h * 64;
  const char* Ksrc = (const char*)(Qb + 768);
  const char* Vsrc = (const char*)(VT + (size_t)(b * 12 + h) * 64 * T);

  __shared__ __align__(16) char smem[49152];  // 3 buffers x (K 8KB | V 8KB)

  const int nt = qblk + 1;

  short8 qf[2];
#pragma unroll
  for (int s = 0; s < 2; s++)
    qf[s] = *(const short8*)(Qb + (size_t)qrow * C3 + s * 32 + g * 8);

  const int kvb = (qi >> 2) * 8 + (qi & 3);
  const int srow = lane >> 3;
  // stage-source swizzle per j (c_ = w*2+j, c_&1 = j):
  const unsigned sw0 = (unsigned)(((lane & 7) ^ (srow & 3)) << 4);
  const unsigned sw1 = (unsigned)(((lane & 7) ^ ((srow & 3) | 4)) << 4);

  float m_run = -1e30f, l_run = 0.f;
  floatx4 o[4] = {};

#define STAGE(t)                                                                    \
  {                                                                                 \
    char* base_ = smem + ((t) % 3) * 16384;                                         \
    const int kv0_ = (t) * 64;                                                      \
    _Pragma("unroll")                                                               \
    for (int j = 0; j < 2; j++) {                                                   \
      const int c_ = w * 2 + j;                                                     \
      const unsigned sw_ = j ? sw1 : sw0;                                           \
      GLDS16(Ksrc + (size_t)(kv0_ + c_ * 8 + srow) * 4608 + sw_, base_ + c_ * 1024); \
      GLDS16(Vsrc + (size_t)(c_ * 8 + srow) * 4096 + kv0_ * 2 + sw_,                \
             base_ + 8192 + c_ * 1024);                                             \
    }                                                                               \
  }

  STAGE(0);
  if (nt > 1) STAGE(1);

  for (int t = 0; t < nt; t++) {
    if (t + 1 < nt) asm volatile("s_waitcnt vmcnt(4)");
    else asm volatile("s_waitcnt vmcnt(0)");
    __syncthreads();
    if (t + 2 < nt) STAGE(t + 2);

    const char* Kl = smem + (t % 3) * 16384;
    const char* Vl = Kl + 8192;
    const int kv0 = t * 64;

    short8 kf[8];
#pragma unroll
    for (int c = 0; c < 4; c++) {
      const int R = kvb + (c & 1) * 4 + (c >> 1) * 32;
      const int gR = (R & 3) | (((R >> 3) & 1) << 2);
#pragma unroll
      for (int s = 0; s < 2; s++)
        kf[c * 2 + s] = *(const short8*)(Kl + R * 128 + (((s * 4 + g) ^ gR) << 4));
    }
    short8 vfr[8];
#pragma unroll
    for (int ks = 0; ks < 2; ks++)
#pragma unroll
      for (int n = 0; n < 4; n++) {
        const int R2 = n * 16 + qi;
        const int gR2 = (R2 & 3) | (((R2 >> 3) & 1) << 2);
        vfr[ks * 4 + n] =
            *(const short8*)(Vl + R2 * 128 + (((ks * 4 + g) ^ gR2) << 4));
      }

    floatx4 sacc[4] = {};
#pragma unroll
    for (int c = 0; c < 4; c++)
#pragma unroll
      for (int s = 0; s < 2; s++)
        sacc[c] =
            __builtin_amdgcn_mfma_f32_16x16x32_bf16(kf[c * 2 + s], qf[s], sacc[c], 0, 0, 0);

    if (kv0 + 63 > q0w) {
#pragma unroll
      for (int c = 0; c < 4; c++)
#pragma unroll
        for (int r = 0; r < 4; r++) {
          const int kv = kv0 + g * 8 + (c & 1) * 4 + r + (c >> 1) * 32;
          if (kv > qrow) sacc[c][r] = -1e30f;
        }
    }
    float mx = sacc[0][0];
#pragma unroll
    for (int c = 0; c < 4; c++)
#pragma unroll
      for (int r = 0; r < 4; r++) mx = fmaxf(mx, sacc[c][r]);
    mx = fmaxf(mx, __shfl_xor(mx, 16));
    mx = fmaxf(mx, __shfl_xor(mx, 32));
    mx *= 0.125f;
    const float mn = fmaxf(m_run, mx);
    const float al = __expf(m_run - mn);
    float ps = 0.f;
    unsigned pk[8];
#pragma unroll
    for (int c = 0; c < 4; c++) {
      float p0 = __expf(fmaf(sacc[c][0], 0.125f, -mn));
      float p1 = __expf(fmaf(sacc[c][1], 0.125f, -mn));
      float p2 = __expf(fmaf(sacc[c][2], 0.125f, -mn));
      float p3 = __expf(fmaf(sacc[c][3], 0.125f, -mn));
      ps += (p0 + p1) + (p2 + p3);
      pk[c * 2] = cvtpk(p0, p1);
      pk[c * 2 + 1] = cvtpk(p2, p3);
    }
    ps += __shfl_xor(ps, 16);
    ps += __shfl_xor(ps, 32);
    l_run = l_run * al + ps;
    m_run = mn;
#pragma unroll
    for (int n = 0; n < 4; n++) o[n] *= al;

#pragma unroll
    for (int ks = 0; ks < 2; ks++) {
      uintx4 pu;
      pu.x = pk[ks * 4 + 0];
      pu.y = pk[ks * 4 + 1];
      pu.z = pk[ks * 4 + 2];
      pu.w = pk[ks * 4 + 3];
      const short8 pf = __builtin_bit_cast(short8, pu);
#pragma unroll
      for (int n = 0; n < 4; n++)
        o[n] = __builtin_amdgcn_mfma_f32_16x16x32_bf16(vfr[ks * 4 + n], pf, o[n], 0, 0, 0);
    }
  }
#undef STAGE

  const float inv = 1.0f / l_run;
  bf16* yr = y + (size_t)(b * T + qrow) * 768 + h * 64;
#pragma unroll
  for (int n = 0; n < 4; n++) {
    uint2 pr;
    pr.x = cvtpk(o[n][0] * inv, o[n][1] * inv);
    pr.y = cvtpk(o[n][2] * inv, o[n][3] * inv);
    *(uint2*)(yr + n * 16 + g * 4) = pr;
  }
}

// ---------------- host side
extern "C" void kernel_launch(void* const* d_in, const int* in_sizes, int n_in,
                              void* d_out, int out_size, void* d_ws, size_t ws_size,
                              hipStream_t stream) {
  const float* x      = (const float*)d_in[0];
  const float* ln1_g  = (const float*)d_in[1];
  const float* ln1_b  = (const float*)d_in[2];
  const float* w_attn = (const float*)d_in[3];
  const float* b_attn = (const float*)d_in[4];
  const float* w_proj = (const float*)d_in[5];
  const float* b_proj = (const float*)d_in[6];
  const float* ln2_g  = (const float*)d_in[7];
  const float* ln2_b  = (const float*)d_in[8];
  const float* w_fc   = (const float*)d_in[9];
  const float* b_fc   = (const float*)d_in[10];
  const float* w_fc2  = (const float*)d_in[11];
  const float* b_fc2  = (const float*)d_in[12];
  float* out = (float*)d_out;

  const int M = 4096;  // B*T
  char* p = (char*)d_ws;
  bf16* wT_attn = (bf16*)p; p += (size_t)2304 * 768 * 2;
  bf16* wT_proj = (bf16*)p; p += (size_t)768 * 768 * 2;
  bf16* wT_fc   = (bf16*)p; p += (size_t)3072 * 768 * 2;
  bf16* wT_fc2  = (bf16*)p; p += (size_t)768 * 3072 * 2;
  bf16* h       = (bf16*)p; p += (size_t)M * 768 * 2;
  bf16* qkv     = (bf16*)p;
  bf16* yb      = (bf16*)(p + (size_t)M * 2304 * 2);
  bf16* act     = qkv;      p += (size_t)M * 2304 * 2 + (size_t)M * 768 * 2;
  float* x1     = (float*)p;
  bf16* VT      = (bf16*)p;  // aliases x1: VT dead before x1 is written

  // weights -> bf16 transposed
  kconvT<<<dim3(2304 / 32, 768 / 32), 256, 0, stream>>>(w_attn, wT_attn, 768, 2304);
  kconvT<<<dim3(768 / 32, 768 / 32), 256, 0, stream>>>(w_proj, wT_proj, 768, 768);
  kconvT<<<dim3(3072 / 32, 768 / 32), 256, 0, stream>>>(w_fc, wT_fc, 768, 3072);
  kconvT<<<dim3(768 / 32, 3072 / 32), 256, 0, stream>>>(w_fc2, wT_fc2, 3072, 768);

  // attention branch
  kln<<<M, 256, 0, stream>>>(x, ln1_g, ln1_b, h);
  kgemm<128, 0><<<dim3(18 * 32), 256, 0, stream>>>(
      h, wT_attn, b_attn, nullptr, qkv, nullptr, M, 2304, 768, 18);
  kxpose<<<dim3(32, 12, 2), 256, 0, stream>>>(qkv, VT);
  kattn<<<dim3(768), 256, 0, stream>>>(qkv, VT, yb);
  kgemm64<<<dim3(64 * 12), 256, 0, stream>>>(
      yb, wT_proj, b_proj, x, x1, M, 768, 768, 12);

  // MLP branch
  kln<<<M, 256, 0, stream>>>(x1, ln2_g, ln2_b, h);
  kgemm<128, 2><<<dim3(24 * 32), 256, 0, stream>>>(
      h, wT_fc, b_fc, nullptr, act, nullptr, M, 3072, 768, 24);
  kgemm64<<<dim3(64 * 12), 256, 0, stream>>>(
      act, wT_fc2, b_fc2, x1, out, M, 768, 3072, 12);
}